// Round 2
// baseline (710.541 us; speedup 1.0000x reference)
//
#include <hip/hip_runtime.h>
#include <hip/hip_bf16.h>

typedef __bf16 bf16;
typedef unsigned short u16;
typedef bf16 bf16x8 __attribute__((ext_vector_type(8)));
typedef u16  u16x8  __attribute__((ext_vector_type(8)));
typedef float f32x4 __attribute__((ext_vector_type(4)));

#define MFMA16(a,b,c) __builtin_amdgcn_mfma_f32_16x16x32_bf16((a),(b),(c),0,0,0)

// W (f32 [c][d]) -> bf16 transposed [which][d][c]
__global__ void cvt_w(const float* __restrict__ Wq, const float* __restrict__ Wk,
                      const float* __restrict__ Wv, bf16* __restrict__ Wbt) {
    int idx = blockIdx.x * 256 + threadIdx.x;
    int which = idx >> 16;
    int rem = idx & 65535;
    int c = rem >> 8, d = rem & 255;
    const float* W = (which == 0) ? Wq : (which == 1) ? Wk : Wv;
    Wbt[(size_t)which * 65536 + d * 256 + c] = (bf16)W[c * 256 + d];
}

// ---------------------------------------------------------------- QKV GEMM
// [32768 x 256] @ [256 x 256] -> Q,K (token-major) and V transposed per config.
__global__ __launch_bounds__(256, 2)
void qkv_gemm(const float* __restrict__ x, const bf16* __restrict__ Wbt,
              bf16* __restrict__ Qb, bf16* __restrict__ Kb,
              bf16* __restrict__ Vt1, bf16* __restrict__ Vt2, bf16* __restrict__ Vt4) {
    __shared__ __align__(16) u16 lA[64 * 136];
    __shared__ __align__(16) u16 lB[64 * 136];
    int mt = blockIdx.x, nt = blockIdx.y, which = blockIdx.z;
    int tid = threadIdx.x, wv = tid >> 6, lane = tid & 63;
    int l15 = lane & 15, quad = lane >> 4;

    f32x4 acc[4] = {};
    const float* Ax = x + (size_t)(mt * 64) * 256;
    const bf16* Bb = Wbt + (size_t)which * 65536 + (size_t)(nt * 64) * 256;
    int row = tid >> 2, c0 = (tid & 3) * 32;

    for (int kh = 0; kh < 2; kh++) {
        __syncthreads();
        #pragma unroll
        for (int i = 0; i < 4; i++) {
            float4 f0 = *(const float4*)(Ax + row * 256 + kh * 128 + c0 + i * 8);
            float4 f1 = *(const float4*)(Ax + row * 256 + kh * 128 + c0 + i * 8 + 4);
            bf16x8 v;
            v[0] = (bf16)f0.x; v[1] = (bf16)f0.y; v[2] = (bf16)f0.z; v[3] = (bf16)f0.w;
            v[4] = (bf16)f1.x; v[5] = (bf16)f1.y; v[6] = (bf16)f1.z; v[7] = (bf16)f1.w;
            *(bf16x8*)((bf16*)lA + row * 136 + c0 + i * 8) = v;
            *(bf16x8*)((bf16*)lB + row * 136 + c0 + i * 8) =
                *(const bf16x8*)(Bb + row * 256 + kh * 128 + c0 + i * 8);
        }
        __syncthreads();
        #pragma unroll
        for (int ks = 0; ks < 4; ks++) {
            bf16x8 a = *(const bf16x8*)((bf16*)lA + (wv * 16 + l15) * 136 + ks * 32 + quad * 8);
            #pragma unroll
            for (int ns = 0; ns < 4; ns++) {
                bf16x8 b2 = *(const bf16x8*)((bf16*)lB + (ns * 16 + l15) * 136 + ks * 32 + quad * 8);
                acc[ns] = MFMA16(a, b2, acc[ns]);
            }
        }
    }
    if (which < 2) {
        bf16* outp = (which == 0) ? Qb : Kb;
        #pragma unroll
        for (int ns = 0; ns < 4; ns++)
            #pragma unroll
            for (int r = 0; r < 4; r++) {
                int tok = mt * 64 + wv * 16 + quad * 4 + r;
                int col = nt * 64 + ns * 16 + l15;
                outp[(size_t)tok * 256 + col] = (bf16)acc[ns][r];
            }
    } else {
        #pragma unroll
        for (int ns = 0; ns < 4; ns++)
            #pragma unroll
            for (int r = 0; r < 4; r++) {
                int tok = mt * 64 + wv * 16 + quad * 4 + r;   // tok & 3 == r
                int col = nt * 64 + ns * 16 + l15;
                bf16 v = (bf16)acc[ns][r];
                Vt1[(size_t)col * 32768 + tok] = v;
                if ((r & 1) == 0) Vt2[(size_t)col * 16384 + (tok >> 1)] = v;
                if (r == 0)       Vt4[(size_t)col * 8192  + (tok >> 2)] = v;
            }
    }
}

// ---------------------------------------------------------------- attention
// block = 64 q-rows x one 512-key chunk of one segment. 4 waves x 16 q each.
// Swapped operands: S^T = K Q^T (C: row=key, col=q); O^T = V^T P^T.
__global__ __launch_bounds__(256, 3)
void attn(const bf16* __restrict__ Qb, const bf16* __restrict__ Kb,
          const bf16* __restrict__ Vt1, const bf16* __restrict__ Vt2,
          const bf16* __restrict__ Vt4,
          float* __restrict__ out, float* __restrict__ sums) {
    __shared__ __align__(16) u16 K_l[32 * 258];   // 16512 B
    __shared__ __align__(16) u16 V_l[256 * 34];   // 17408 B

    const int qt = 31 - (int)blockIdx.x;
    const int nkt32 = 2 * (qt + 1);
    const int c0 = (int)blockIdx.y * 16;
    if (c0 >= nkt32) return;
    const int cend = min(c0 + 16, nkt32);

    int seg = blockIdx.z;
    int lr, b, s, w;
    if (seg < 16)      { lr = 0; s = seg >> 2;        b = seg & 3;        w = 2048; }
    else if (seg < 24) { lr = 1; s = (seg - 16) >> 2; b = (seg - 16) & 3; w = 4096; }
    else               { lr = 2; s = 0;               b = seg - 24;       w = 8192; }
    const int rr = 1 << lr;
    const size_t base = (size_t)b * 8192 + (size_t)s * w;       // token = base + j*rr
    const int ncol = 32768 >> lr;
    const size_t pbase = (size_t)b * (8192 >> lr) + (size_t)s * 2048;
    const bf16* Vt = (lr == 0) ? Vt1 : (lr == 1) ? Vt2 : Vt4;

    const int tid = threadIdx.x, wv = tid >> 6, lane = tid & 63;
    const int l15 = lane & 15, quad = lane >> 4;

    // Q B-fragments: n = q = l15, k = quad*8+j
    const int qi = qt * 64 + wv * 16 + l15;
    const bf16* qp = Qb + (base + (size_t)qi * rr) * 256 + quad * 8;
    bf16x8 qf[8];
    #pragma unroll
    for (int ks = 0; ks < 8; ks++) qf[ks] = *(const bf16x8*)(qp + ks * 32);

    f32x4 o[16] = {};
    float m_run = -1e30f, l_run = 0.f;

    const int krow = tid & 31, kcol = (tid >> 5) * 32;   // K staging map
    u16x8 kreg[4], vreg[4];
    const u16* Kb16 = (const u16*)Kb;
    const u16* Vt16 = (const u16*)Vt;

    {   // prefetch first tile
        const u16* kp = Kb16 + (base + (size_t)(c0 * 32 + krow) * rr) * 256 + kcol;
        #pragma unroll
        for (int i = 0; i < 4; i++) kreg[i] = *(const u16x8*)(kp + i * 8);
        const u16* vp = Vt16 + (size_t)tid * ncol + pbase + c0 * 32;
        #pragma unroll
        for (int i = 0; i < 4; i++) vreg[i] = *(const u16x8*)(vp + i * 8);
    }

    for (int kt = c0; kt < cend; kt++) {
        __syncthreads();
        #pragma unroll
        for (int i = 0; i < 4; i++)
            *(u16x8*)(K_l + krow * 258 + kcol + i * 8) = kreg[i];
        #pragma unroll
        for (int i = 0; i < 4; i++)
            *(u16x8*)(V_l + tid * 34 + i * 8) = vreg[i];
        __syncthreads();
        if (kt + 1 < cend) {   // prefetch next tile (overlaps compute below)
            const u16* kp = Kb16 + (base + (size_t)((kt + 1) * 32 + krow) * rr) * 256 + kcol;
            #pragma unroll
            for (int i = 0; i < 4; i++) kreg[i] = *(const u16x8*)(kp + i * 8);
            const u16* vp = Vt16 + (size_t)tid * ncol + pbase + (kt + 1) * 32;
            #pragma unroll
            for (int i = 0; i < 4; i++) vreg[i] = *(const u16x8*)(vp + i * 8);
        }

        // S^T: A = K rows (m=key), B = Q (n=q)
        f32x4 sf[2] = {};
        #pragma unroll
        for (int ks = 0; ks < 8; ks++) {
            #pragma unroll
            for (int kb = 0; kb < 2; kb++) {
                bf16x8 kf = *(const bf16x8*)((const bf16*)K_l + (kb * 16 + l15) * 258 + ks * 32 + quad * 8);
                sf[kb] = MFMA16(kf, qf[ks], sf[kb]);
            }
        }
        // scale + causal mask; lane element (key = kt*32+kb*16+quad*4+r, q = qi)
        float mx = -1e30f;
        #pragma unroll
        for (int kb = 0; kb < 2; kb++)
            #pragma unroll
            for (int r = 0; r < 4; r++) {
                float v = sf[kb][r] * 0.0625f;
                if (kt >= 2 * qt) {
                    int key = kt * 32 + kb * 16 + quad * 4 + r;
                    if (key > qi) v = -1e30f;
                }
                sf[kb][r] = v;
                mx = fmaxf(mx, v);
            }
        mx = fmaxf(mx, __shfl_xor(mx, 16));
        mx = fmaxf(mx, __shfl_xor(mx, 32));
        float mnew = fmaxf(m_run, mx);
        float a = __expf(m_run - mnew);
        m_run = mnew;
        float rs = 0.f;
        #pragma unroll
        for (int kb = 0; kb < 2; kb++)
            #pragma unroll
            for (int r = 0; r < 4; r++) {
                float e = __expf(sf[kb][r] - mnew);
                sf[kb][r] = e;
                rs += e;
            }
        rs += __shfl_xor(rs, 16);
        rs += __shfl_xor(rs, 32);
        l_run = l_run * a + rs;
        #pragma unroll
        for (int f = 0; f < 16; f++)
            #pragma unroll
            for (int r = 0; r < 4; r++) o[f][r] *= a;

        // build P^T B-fragment via cross-quad shuffles (no LDS, no barrier)
        bf16x8 pb;
        {
            int srclo = l15 + 32 * (quad & 1);
            #pragma unroll
            for (int j = 0; j < 8; j++) {
                int srcl = srclo + (j >> 2) * 16;
                float e0 = __shfl(sf[0][j & 3], srcl, 64);
                float e1 = __shfl(sf[1][j & 3], srcl, 64);
                pb[j] = (bf16)((quad >> 1) ? e1 : e0);
            }
        }
        // O^T += V^T P^T
        #pragma unroll
        for (int f = 0; f < 16; f++) {
            bf16x8 vf = *(const bf16x8*)((const bf16*)V_l + (f * 16 + l15) * 34 + quad * 8);
            o[f] = MFMA16(vf, pb, o[f]);
        }
    }

    // epilogue: atomically merge exp-weighted partials
    float wsc = __expf(m_run);
    float denom = l_run * wsc;
    size_t tok = base + (size_t)qi * rr;
    if (quad == 0) atomicAdd(sums + tok, denom);
    float* orow = out + tok * 256 + quad * 4;
    #pragma unroll
    for (int f = 0; f < 16; f++)
        #pragma unroll
        for (int r = 0; r < 4; r++)
            atomicAdd(orow + f * 16 + r, o[f][r] * wsc);
}

// ---------------------------------------------------------------- finalize
__global__ void finalize(float* __restrict__ out, const float* __restrict__ sums) {
    int idx = blockIdx.x * 256 + threadIdx.x;   // 2M float4
    float inv = 1.0f / sums[idx >> 6];
    float4 v = ((float4*)out)[idx];
    v.x *= inv; v.y *= inv; v.z *= inv; v.w *= inv;
    ((float4*)out)[idx] = v;
}

// ---------------------------------------------------------------- launch
extern "C" void kernel_launch(void* const* d_in, const int* in_sizes, int n_in,
                              void* d_out, int out_size, void* d_ws, size_t ws_size,
                              hipStream_t stream) {
    const float* x  = (const float*)d_in[0];
    const float* Wq = (const float*)d_in[1];
    const float* Wk = (const float*)d_in[2];
    const float* Wv = (const float*)d_in[3];
    float* out = (float*)d_out;

    char* ws = (char*)d_ws;
    bf16* Qb   = (bf16*)(ws);                       // 16 MB
    bf16* Kb   = (bf16*)(ws + 16777216);            // 16 MB
    bf16* Vt1  = (bf16*)(ws + 33554432);            // 16 MB  [256][32768]
    bf16* Vt2  = (bf16*)(ws + 50331648);            //  8 MB  [256][16384]
    bf16* Vt4  = (bf16*)(ws + 58720256);            //  4 MB  [256][8192]
    bf16* Wbt  = (bf16*)(ws + 62914560);            // 384 KB
    float* sums = (float*)(ws + 63307776);          // 128 KB

    hipMemsetAsync(out, 0, (size_t)out_size * sizeof(float), stream);
    hipMemsetAsync(sums, 0, 32768 * sizeof(float), stream);

    cvt_w<<<768, 256, 0, stream>>>(Wq, Wk, Wv, Wbt);
    qkv_gemm<<<dim3(512, 4, 3), 256, 0, stream>>>(x, Wbt, Qb, Kb, Vt1, Vt2, Vt4);
    attn<<<dim3(32, 4, 28), 256, 0, stream>>>(Qb, Kb, Vt1, Vt2, Vt4, out, sums);
    finalize<<<8192, 256, 0, stream>>>(out, sums);
}

// Round 3
// 696.374 us; speedup vs baseline: 1.0203x; 1.0203x over previous
//
#include <hip/hip_runtime.h>
#include <hip/hip_bf16.h>

typedef __bf16 bf16;
typedef unsigned short u16;
typedef bf16 bf16x8 __attribute__((ext_vector_type(8)));
typedef u16  u16x8  __attribute__((ext_vector_type(8)));
typedef float f32x4 __attribute__((ext_vector_type(4)));

#define MFMA16(a,b,c) __builtin_amdgcn_mfma_f32_16x16x32_bf16((a),(b),(c),0,0,0)
#define QSCALE 0.09016844005625f   // (1/16) * log2(e)

// W (f32 [c][d]) -> bf16 transposed [which][d][c]
__global__ void cvt_w(const float* __restrict__ Wq, const float* __restrict__ Wk,
                      const float* __restrict__ Wv, bf16* __restrict__ Wbt) {
    int idx = blockIdx.x * 256 + threadIdx.x;
    int which = idx >> 16;
    int rem = idx & 65535;
    int c = rem >> 8, d = rem & 255;
    const float* W = (which == 0) ? Wq : (which == 1) ? Wk : Wv;
    Wbt[(size_t)which * 65536 + d * 256 + c] = (bf16)W[c * 256 + d];
}

// ---------------------------------------------------------------- QKV GEMM
// [32768 x 256] @ [256 x 256] -> Q (prescaled), K row-major; V transposed per cfg.
__global__ __launch_bounds__(256, 2)
void qkv_gemm(const float* __restrict__ x, const bf16* __restrict__ Wbt,
              bf16* __restrict__ Qb, bf16* __restrict__ Kb,
              bf16* __restrict__ Vt1, bf16* __restrict__ Vt2, bf16* __restrict__ Vt4) {
    __shared__ __align__(16) u16 lA[64 * 136];
    __shared__ __align__(16) u16 lB[64 * 136];
    int mt = blockIdx.x, nt = blockIdx.y, which = blockIdx.z;
    int tid = threadIdx.x, wv = tid >> 6, lane = tid & 63;
    int l15 = lane & 15, quad = lane >> 4;

    f32x4 acc[4] = {};
    const float* Ax = x + (size_t)(mt * 64) * 256;
    const bf16* Bb = Wbt + (size_t)which * 65536 + (size_t)(nt * 64) * 256;
    int row = tid >> 2, c0 = (tid & 3) * 32;

    for (int kh = 0; kh < 2; kh++) {
        __syncthreads();
        #pragma unroll
        for (int i = 0; i < 4; i++) {
            float4 f0 = *(const float4*)(Ax + row * 256 + kh * 128 + c0 + i * 8);
            float4 f1 = *(const float4*)(Ax + row * 256 + kh * 128 + c0 + i * 8 + 4);
            bf16x8 v;
            v[0] = (bf16)f0.x; v[1] = (bf16)f0.y; v[2] = (bf16)f0.z; v[3] = (bf16)f0.w;
            v[4] = (bf16)f1.x; v[5] = (bf16)f1.y; v[6] = (bf16)f1.z; v[7] = (bf16)f1.w;
            *(bf16x8*)((bf16*)lA + row * 136 + c0 + i * 8) = v;
            *(bf16x8*)((bf16*)lB + row * 136 + c0 + i * 8) =
                *(const bf16x8*)(Bb + row * 256 + kh * 128 + c0 + i * 8);
        }
        __syncthreads();
        #pragma unroll
        for (int ks = 0; ks < 4; ks++) {
            bf16x8 a = *(const bf16x8*)((bf16*)lA + (wv * 16 + l15) * 136 + ks * 32 + quad * 8);
            #pragma unroll
            for (int ns = 0; ns < 4; ns++) {
                bf16x8 b2 = *(const bf16x8*)((bf16*)lB + (ns * 16 + l15) * 136 + ks * 32 + quad * 8);
                acc[ns] = MFMA16(a, b2, acc[ns]);
            }
        }
    }

    // Epilogue: stage through LDS for coalesced stores.
    __syncthreads();
    u16* lT = lA;                     // [64][72] u16 (aligned rows)
    float sc = (which == 0) ? QSCALE : 1.0f;
    if (which < 2) {
        // layout [tok][col]
        #pragma unroll
        for (int ns = 0; ns < 4; ns++)
            #pragma unroll
            for (int r = 0; r < 4; r++) {
                bf16 v = (bf16)(acc[ns][r] * sc);
                lT[(wv * 16 + quad * 4 + r) * 72 + ns * 16 + l15] = *(u16*)&v;
            }
        __syncthreads();
        bf16* outp = (which == 0) ? Qb : Kb;
        int tokl = tid >> 2, ch = tid & 3;
        u16x8 v0 = *(u16x8*)(lT + tokl * 72 + ch * 16);
        u16x8 v1 = *(u16x8*)(lT + tokl * 72 + ch * 16 + 8);
        u16* dst = (u16*)outp + (size_t)(mt * 64 + tokl) * 256 + nt * 64 + ch * 16;
        *(u16x8*)dst = v0;
        *(u16x8*)(dst + 8) = v1;
    } else {
        // layout [col][tok]
        #pragma unroll
        for (int ns = 0; ns < 4; ns++)
            #pragma unroll
            for (int r = 0; r < 4; r++) {
                bf16 v = (bf16)acc[ns][r];
                lT[(ns * 16 + l15) * 72 + wv * 16 + quad * 4 + r] = *(u16*)&v;
            }
        __syncthreads();
        int col = tid >> 2, ch = tid & 3;
        int col_g = nt * 64 + col, gtok = mt * 64;
        // Vt1: all 64 tokens of this row
        {
            u16x8 v0 = *(u16x8*)(lT + col * 72 + ch * 16);
            u16x8 v1 = *(u16x8*)(lT + col * 72 + ch * 16 + 8);
            u16* dst = (u16*)Vt1 + (size_t)col_g * 32768 + gtok + ch * 16;
            *(u16x8*)dst = v0; *(u16x8*)(dst + 8) = v1;
        }
        if (ch < 2) {    // Vt2: even tokens
            u16x8 e0, e1;
            #pragma unroll
            for (int i = 0; i < 8; i++) {
                e0[i] = lT[col * 72 + ch * 32 + 2 * i];
                e1[i] = lT[col * 72 + ch * 32 + 2 * (i + 8)];
            }
            u16* dst = (u16*)Vt2 + (size_t)col_g * 16384 + (gtok >> 1) + ch * 16;
            *(u16x8*)dst = e0; *(u16x8*)(dst + 8) = e1;
        }
        if (ch == 0) {   // Vt4: tokens % 4 == 0
            u16x8 e0, e1;
            #pragma unroll
            for (int i = 0; i < 8; i++) {
                e0[i] = lT[col * 72 + 4 * i];
                e1[i] = lT[col * 72 + 4 * (i + 8)];
            }
            u16* dst = (u16*)Vt4 + (size_t)col_g * 8192 + (gtok >> 2);
            *(u16x8*)dst = e0; *(u16x8*)(dst + 8) = e1;
        }
    }
}

// ---------------------------------------------------------------- attention
// One block = 64 q-rows of one (seg, qt); full K-range; NO LDS, NO barriers.
// All MFMA fragments loaded directly from global (L2-served).
__global__ __launch_bounds__(256, 3)
void attn(const bf16* __restrict__ Qb, const bf16* __restrict__ Kb,
          const bf16* __restrict__ Vt1, const bf16* __restrict__ Vt2,
          const bf16* __restrict__ Vt4,
          float* __restrict__ O1, float* __restrict__ O2, float* __restrict__ O4,
          float* __restrict__ D1, float* __restrict__ D2, float* __restrict__ D4) {
    const int item = (int)blockIdx.x;
    const int qt = 31 - (item / 28);            // heavy rows dispatched first
    const int seg = item % 28;

    int lr, b, s, w;
    if (seg < 16)      { lr = 0; s = seg >> 2;        b = seg & 3;        w = 2048; }
    else if (seg < 24) { lr = 1; s = (seg - 16) >> 2; b = (seg - 16) & 3; w = 4096; }
    else               { lr = 2; s = 0;               b = seg - 24;       w = 8192; }
    const int rr = 1 << lr;
    const size_t base = (size_t)b * 8192 + (size_t)s * w;       // token = base + j*rr
    const int ncol = 32768 >> lr;
    const size_t pbase = (size_t)b * (8192 >> lr) + (size_t)s * 2048;
    const bf16* Vt = (lr == 0) ? Vt1 : (lr == 1) ? Vt2 : Vt4;
    float* Op = (lr == 0) ? O1 : (lr == 1) ? O2 : O4;
    float* Dp = (lr == 0) ? D1 : (lr == 1) ? D2 : D4;

    const int tid = threadIdx.x, wv = tid >> 6, lane = tid & 63;
    const int l15 = lane & 15, quad = lane >> 4;

    // Q B-fragments (n = q = l15, k = quad*8 + j), K=256 -> 8 frags
    const int qi = qt * 64 + wv * 16 + l15;
    const bf16* qp = Qb + (base + (size_t)qi * rr) * 256 + quad * 8;
    bf16x8 qf[8];
    #pragma unroll
    for (int ks = 0; ks < 8; ks++) qf[ks] = *(const bf16x8*)(qp + ks * 32);

    f32x4 o[16] = {};
    float m_run = -1e30f, l_run = 0.f;

    const bf16* Kbase = Kb + base * 256 + quad * 8;   // + key*rr*256 + ks*32
    const bf16* Vbase = Vt + pbase + quad * 8;        // + d*ncol + kt*32

    const int nkt = 2 * (qt + 1);
    for (int kt = 0; kt < nkt; kt++) {
        // S^T = K Q^T : A = K rows (m=key), B = Q (n=q)
        f32x4 sf[2] = {};
        #pragma unroll
        for (int ks = 0; ks < 8; ks++) {
            #pragma unroll
            for (int kb = 0; kb < 2; kb++) {
                int key = kt * 32 + kb * 16 + l15;
                bf16x8 kf = *(const bf16x8*)(Kbase + (size_t)key * rr * 256 + ks * 32);
                sf[kb] = MFMA16(kf, qf[ks], sf[kb]);
            }
        }
        // causal mask (only the two diagonal tiles); running max
        float mx = -1e30f;
        #pragma unroll
        for (int kb = 0; kb < 2; kb++)
            #pragma unroll
            for (int r = 0; r < 4; r++) {
                float v = sf[kb][r];
                if (kt >= 2 * qt) {
                    int key = kt * 32 + kb * 16 + quad * 4 + r;
                    if (key > qi) v = -1e30f;
                }
                sf[kb][r] = v;
                mx = fmaxf(mx, v);
            }
        mx = fmaxf(mx, __shfl_xor(mx, 16));
        mx = fmaxf(mx, __shfl_xor(mx, 32));
        float mold = m_run;
        float mnew = fmaxf(mold, mx);
        m_run = mnew;
        float a = exp2f(mold - mnew);
        float rs = 0.f;
        #pragma unroll
        for (int kb = 0; kb < 2; kb++)
            #pragma unroll
            for (int r = 0; r < 4; r++) {
                float e = exp2f(sf[kb][r] - mnew);
                sf[kb][r] = e;
                rs += e;
            }
        rs += __shfl_xor(rs, 16);
        rs += __shfl_xor(rs, 32);
        l_run = l_run * a + rs;
        if (__any(mnew > mold)) {
            #pragma unroll
            for (int f = 0; f < 16; f++)
                #pragma unroll
                for (int r = 0; r < 4; r++) o[f][r] *= a;
        }
        // P^T B-fragment via cross-quad shuffles
        bf16x8 pb;
        {
            int srclo = l15 + 32 * (quad & 1);
            #pragma unroll
            for (int j = 0; j < 8; j++) {
                int srcl = srclo + (j >> 2) * 16;
                float e0 = __shfl(sf[0][j & 3], srcl, 64);
                float e1 = __shfl(sf[1][j & 3], srcl, 64);
                pb[j] = (bf16)((quad >> 1) ? e1 : e0);
            }
        }
        // O^T += V^T P^T : A = V^T (m=d, k=key) direct from global
        #pragma unroll
        for (int f = 0; f < 16; f++) {
            bf16x8 vf = *(const bf16x8*)(Vbase + (size_t)(f * 16 + l15) * ncol + kt * 32);
            o[f] = MFMA16(vf, pb, o[f]);
        }
    }

    // epilogue: direct (collision-free) store of normalized partial + denom
    float invl = 1.0f / l_run;
    size_t pos = pbase + (size_t)qi;
    if (quad == 0) Dp[pos] = l_run * exp2f(m_run);
    float* orow = Op + pos * 256 + quad * 4;
    #pragma unroll
    for (int f = 0; f < 16; f++) {
        f32x4 v;
        #pragma unroll
        for (int r = 0; r < 4; r++) v[r] = o[f][r] * invl;
        *(f32x4*)(orow + f * 16) = v;
    }
}

// ---------------------------------------------------------------- finalize
// out = (O1*d1 + O2*d2 + O4*d4) / (d1+d2+d4); O1 lives in d_out already.
__global__ void finalize(float* __restrict__ out, const float* __restrict__ O2,
                         const float* __restrict__ O4,
                         const float* __restrict__ D1, const float* __restrict__ D2,
                         const float* __restrict__ D4) {
    int g = blockIdx.x * 256 + threadIdx.x;     // 32768 tokens * 64 chunks
    int t = g >> 6, dc = (g & 63) * 4;
    int b = t >> 13, n = t & 8191;
    float d1 = D1[t];
    float4 o1 = *(float4*)(out + (size_t)t * 256 + dc);
    float ax = o1.x * d1, ay = o1.y * d1, az = o1.z * d1, aw = o1.w * d1;
    float den = d1;
    if ((n & 1) == 0) {
        int pos2 = b * 4096 + (n >> 12) * 2048 + ((n & 4095) >> 1);
        float d2 = D2[pos2];
        const float4 o2 = *(const float4*)(O2 + (size_t)pos2 * 256 + dc);
        ax += o2.x * d2; ay += o2.y * d2; az += o2.z * d2; aw += o2.w * d2;
        den += d2;
    }
    if ((n & 3) == 0) {
        int pos4 = b * 2048 + (n >> 2);
        float d4 = D4[pos4];
        const float4 o4 = *(const float4*)(O4 + (size_t)pos4 * 256 + dc);
        ax += o4.x * d4; ay += o4.y * d4; az += o4.z * d4; aw += o4.w * d4;
        den += d4;
    }
    float inv = 1.0f / den;
    float4 r; r.x = ax * inv; r.y = ay * inv; r.z = az * inv; r.w = aw * inv;
    *(float4*)(out + (size_t)t * 256 + dc) = r;
}

// ---------------------------------------------------------------- launch
extern "C" void kernel_launch(void* const* d_in, const int* in_sizes, int n_in,
                              void* d_out, int out_size, void* d_ws, size_t ws_size,
                              hipStream_t stream) {
    const float* x  = (const float*)d_in[0];
    const float* Wq = (const float*)d_in[1];
    const float* Wk = (const float*)d_in[2];
    const float* Wv = (const float*)d_in[3];
    float* out = (float*)d_out;

    char* ws = (char*)d_ws;
    bf16* Qb   = (bf16*)(ws);                        // 16 MB
    bf16* Kb   = (bf16*)(ws + 16777216);             // 16 MB
    bf16* Vt1  = (bf16*)(ws + 33554432);             // 16 MB  [256][32768]
    bf16* Vt2  = (bf16*)(ws + 50331648);             //  8 MB  [256][16384]
    bf16* Vt4  = (bf16*)(ws + 58720256);             //  4 MB  [256][8192]
    bf16* Wbt  = (bf16*)(ws + 62914560);             // 384 KB
    float* O2  = (float*)(ws + 63307776);            // 16 MB  [16384][256]
    float* O4  = (float*)(ws + 80084992);            //  8 MB  [8192][256]
    float* D1  = (float*)(ws + 88473600);            // 128 KB
    float* D2  = (float*)(ws + 88604672);            //  64 KB
    float* D4  = (float*)(ws + 88670208);            //  32 KB

    cvt_w<<<768, 256, 0, stream>>>(Wq, Wk, Wv, Wbt);
    qkv_gemm<<<dim3(512, 4, 3), 256, 0, stream>>>(x, Wbt, Qb, Kb, Vt1, Vt2, Vt4);
    attn<<<896, 256, 0, stream>>>(Qb, Kb, Vt1, Vt2, Vt4, out, O2, O4, D1, D2, D4);
    finalize<<<8192, 256, 0, stream>>>(out, O2, O4, D1, D2, D4);
}

// Round 4
// 577.975 us; speedup vs baseline: 1.2294x; 1.2049x over previous
//
#include <hip/hip_runtime.h>
#include <hip/hip_bf16.h>

typedef __bf16 bf16;
typedef unsigned short u16;
typedef bf16 bf16x8 __attribute__((ext_vector_type(8)));
typedef u16  u16x8  __attribute__((ext_vector_type(8)));
typedef u16  u16x4  __attribute__((ext_vector_type(4)));
typedef float f32x4 __attribute__((ext_vector_type(4)));

#define MFMA16(a,b,c) __builtin_amdgcn_mfma_f32_16x16x32_bf16((a),(b),(c),0,0,0)
#define QSCALE 0.09016844005625f   // (1/16) * log2(e)

// W (f32 [c][d]) -> bf16 transposed [which][d][c]
__global__ void cvt_w(const float* __restrict__ Wq, const float* __restrict__ Wk,
                      const float* __restrict__ Wv, bf16* __restrict__ Wbt) {
    int idx = blockIdx.x * 256 + threadIdx.x;
    int which = idx >> 16;
    int rem = idx & 65535;
    int c = rem >> 8, d = rem & 255;
    const float* W = (which == 0) ? Wq : (which == 1) ? Wk : Wv;
    Wbt[(size_t)which * 65536 + d * 256 + c] = (bf16)W[c * 256 + d];
}

// ---------------------------------------------------------------- QKV GEMM
// [32768 x 256] @ [256 x 256] -> Q (prescaled), K row-major; V^T tiled per cfg:
// Vtt_r[segi][kt][256 d][32 keys]  (each 32-key tile = contiguous 16 KB).
__global__ __launch_bounds__(256, 2)
void qkv_gemm(const float* __restrict__ x, const bf16* __restrict__ Wbt,
              bf16* __restrict__ Qb, bf16* __restrict__ Kb,
              bf16* __restrict__ Vtt1, bf16* __restrict__ Vtt2, bf16* __restrict__ Vtt4) {
    __shared__ __align__(16) u16 lA[64 * 136];
    __shared__ __align__(16) u16 lB[64 * 136];
    int mt = blockIdx.x, nt = blockIdx.y, which = blockIdx.z;
    int tid = threadIdx.x, wv = tid >> 6, lane = tid & 63;
    int l15 = lane & 15, quad = lane >> 4;

    f32x4 acc[4] = {};
    const float* Ax = x + (size_t)(mt * 64) * 256;
    const bf16* Bb = Wbt + (size_t)which * 65536 + (size_t)(nt * 64) * 256;
    int row = tid >> 2, c0 = (tid & 3) * 32;

    for (int kh = 0; kh < 2; kh++) {
        __syncthreads();
        #pragma unroll
        for (int i = 0; i < 4; i++) {
            float4 f0 = *(const float4*)(Ax + row * 256 + kh * 128 + c0 + i * 8);
            float4 f1 = *(const float4*)(Ax + row * 256 + kh * 128 + c0 + i * 8 + 4);
            bf16x8 v;
            v[0] = (bf16)f0.x; v[1] = (bf16)f0.y; v[2] = (bf16)f0.z; v[3] = (bf16)f0.w;
            v[4] = (bf16)f1.x; v[5] = (bf16)f1.y; v[6] = (bf16)f1.z; v[7] = (bf16)f1.w;
            *(bf16x8*)((bf16*)lA + row * 136 + c0 + i * 8) = v;
            *(bf16x8*)((bf16*)lB + row * 136 + c0 + i * 8) =
                *(const bf16x8*)(Bb + row * 256 + kh * 128 + c0 + i * 8);
        }
        __syncthreads();
        #pragma unroll
        for (int ks = 0; ks < 4; ks++) {
            bf16x8 a = *(const bf16x8*)((bf16*)lA + (wv * 16 + l15) * 136 + ks * 32 + quad * 8);
            #pragma unroll
            for (int ns = 0; ns < 4; ns++) {
                bf16x8 b2 = *(const bf16x8*)((bf16*)lB + (ns * 16 + l15) * 136 + ks * 32 + quad * 8);
                acc[ns] = MFMA16(a, b2, acc[ns]);
            }
        }
    }

    // Epilogue through LDS for coalesced stores.
    __syncthreads();
    u16* lT = lA;                     // [64][72] u16
    float sc = (which == 0) ? QSCALE : 1.0f;
    if (which < 2) {
        // layout [tok][col]
        #pragma unroll
        for (int ns = 0; ns < 4; ns++)
            #pragma unroll
            for (int r = 0; r < 4; r++) {
                bf16 v = (bf16)(acc[ns][r] * sc);
                lT[(wv * 16 + quad * 4 + r) * 72 + ns * 16 + l15] = *(u16*)&v;
            }
        __syncthreads();
        bf16* outp = (which == 0) ? Qb : Kb;
        int tokl = tid >> 2, ch = tid & 3;
        u16x8 v0 = *(u16x8*)(lT + tokl * 72 + ch * 16);
        u16x8 v1 = *(u16x8*)(lT + tokl * 72 + ch * 16 + 8);
        u16* dst = (u16*)outp + (size_t)(mt * 64 + tokl) * 256 + nt * 64 + ch * 16;
        *(u16x8*)dst = v0;
        *(u16x8*)(dst + 8) = v1;
    } else {
        // layout [col d][tok]
        #pragma unroll
        for (int ns = 0; ns < 4; ns++)
            #pragma unroll
            for (int r = 0; r < 4; r++) {
                bf16 v = (bf16)acc[ns][r];
                lT[(ns * 16 + l15) * 72 + wv * 16 + quad * 4 + r] = *(u16*)&v;
            }
        __syncthreads();
        int gtok = mt * 64;
        int bL = gtok >> 13, n0 = gtok & 8191;
        int d_l = tid >> 2, q = tid & 3;
        int dg = nt * 64 + d_l;
        {   // cfg1: segs of 2048 consecutive tokens; 2 tiles per block
            int s1 = n0 >> 11, j1 = n0 & 2047;           // j1 multiple of 64
            u16* dst = (u16*)Vtt1 + ((size_t)(bL * 4 + s1) * 64 + (j1 >> 5) + (q >> 1)) * 8192
                       + (size_t)dg * 32 + (q & 1) * 16;
            u16x8 a0 = *(u16x8*)(lT + d_l * 72 + q * 16);
            u16x8 a1 = *(u16x8*)(lT + d_l * 72 + q * 16 + 8);
            *(u16x8*)dst = a0; *(u16x8*)(dst + 8) = a1;
        }
        {   // cfg2: even tokens; 32 compacted keys per block = 1 tile
            int s2 = n0 >> 12, j2 = (n0 & 4095) >> 1;    // multiple of 32
            u16x8 e;
            #pragma unroll
            for (int i = 0; i < 8; i++) e[i] = lT[d_l * 72 + q * 16 + 2 * i];
            u16* dst = (u16*)Vtt2 + ((size_t)(bL * 2 + s2) * 64 + (j2 >> 5)) * 8192
                       + (size_t)dg * 32 + q * 8;
            *(u16x8*)dst = e;
        }
        {   // cfg4: tokens %4==0; 16 compacted keys per block = half tile
            int j4 = n0 >> 2;                            // multiple of 16
            u16x4 e;
            #pragma unroll
            for (int i = 0; i < 4; i++) e[i] = lT[d_l * 72 + q * 16 + 4 * i];
            u16* dst = (u16*)Vtt4 + ((size_t)bL * 64 + (j4 >> 5)) * 8192
                       + (size_t)dg * 32 + (j4 & 31) + q * 4;
            *(u16x4*)dst = e;
        }
    }
}

// ---------------------------------------------------------------- attention
// One block = 64 q-rows of one (seg, qt); LDS-staged K and V^T tiles,
// contiguous global reads, register prefetch, 2 barriers/tile, no atomics.
__global__ __launch_bounds__(256, 4)
void attn(const bf16* __restrict__ Qb, const bf16* __restrict__ Kb,
          const bf16* __restrict__ Vtt1, const bf16* __restrict__ Vtt2,
          const bf16* __restrict__ Vtt4,
          float* __restrict__ O1, float* __restrict__ O2, float* __restrict__ O4,
          float* __restrict__ D1, float* __restrict__ D2, float* __restrict__ D4) {
    __shared__ __align__(16) u16 K_l[32 * 264];   // 16896 B
    __shared__ __align__(16) u16 V_l[256 * 34];   // 17408 B

    const int item = (int)blockIdx.x;
    const int qt = 31 - (item / 28);              // heavy rows first
    const int seg = item % 28;

    int lr, b, s, w;
    if (seg < 16)      { lr = 0; s = seg >> 2;        b = seg & 3;        w = 2048; }
    else if (seg < 24) { lr = 1; s = (seg - 16) >> 2; b = (seg - 16) & 3; w = 4096; }
    else               { lr = 2; s = 0;               b = seg - 24;       w = 8192; }
    const int rr = 1 << lr;
    const size_t base = (size_t)b * 8192 + (size_t)s * w;      // token = base + j*rr
    const size_t pbase = (size_t)b * (8192 >> lr) + (size_t)s * 2048;
    const int segi = (lr == 0) ? (b * 4 + s) : (lr == 1) ? (b * 2 + s) : b;
    const bf16* Vtt = (lr == 0) ? Vtt1 : (lr == 1) ? Vtt2 : Vtt4;
    const u16* Vseg = (const u16*)Vtt + (size_t)segi * 64 * 8192;  // [64 tiles][256][32]
    float* Op = (lr == 0) ? O1 : (lr == 1) ? O2 : O4;
    float* Dp = (lr == 0) ? D1 : (lr == 1) ? D2 : D4;

    const int tid = threadIdx.x, wv = tid >> 6, lane = tid & 63;
    const int l15 = lane & 15, quad = lane >> 4;

    // Q B-fragments (n = q = l15, k = quad*8 + j)
    const int qi = qt * 64 + wv * 16 + l15;
    const bf16* qp = Qb + (base + (size_t)qi * rr) * 256 + quad * 8;
    bf16x8 qf[8];
    #pragma unroll
    for (int ks = 0; ks < 8; ks++) qf[ks] = *(const bf16x8*)(qp + ks * 32);

    f32x4 o[16] = {};
    float m_run = -1e30f, l_run = 0.f;

    // staging maps
    const int krow = tid >> 3, kcol = (tid & 7) * 32;          // K: 32 rows x 512B
    const u16* Kp = (const u16*)Kb + base * 256;
    u16x8 kpre[4], vpre[4];
    {   // prefetch tile 0
        const u16* kp = Kp + (size_t)krow * rr * 256 + kcol;
        #pragma unroll
        for (int i = 0; i < 4; i++) kpre[i] = *(const u16x8*)(kp + i * 8);
        const u16* vp = Vseg + (size_t)tid * 32;               // tile 0, contiguous 16 KB
        #pragma unroll
        for (int i = 0; i < 4; i++) vpre[i] = *(const u16x8*)(vp + i * 8);
    }

    const int nkt = 2 * (qt + 1);
    for (int kt = 0; kt < nkt; kt++) {
        __syncthreads();                    // prev compute done reading LDS
        #pragma unroll
        for (int i = 0; i < 4; i++)
            *(u16x8*)(K_l + krow * 264 + kcol + i * 8) = kpre[i];
        #pragma unroll
        for (int i = 0; i < 4; i++)
            *(u16x8*)(V_l + tid * 34 + i * 8) = vpre[i];
        __syncthreads();
        if (kt + 1 < nkt) {                 // prefetch next tile (overlaps compute)
            const u16* kp = Kp + (size_t)((kt + 1) * 32 + krow) * rr * 256 + kcol;
            #pragma unroll
            for (int i = 0; i < 4; i++) kpre[i] = *(const u16x8*)(kp + i * 8);
            const u16* vp = Vseg + (size_t)(kt + 1) * 8192 + (size_t)tid * 32;
            #pragma unroll
            for (int i = 0; i < 4; i++) vpre[i] = *(const u16x8*)(vp + i * 8);
        }

        // S^T = K Q^T : A = K rows (m=key), B = Q (n=q)
        f32x4 sf[2] = {};
        #pragma unroll
        for (int ks = 0; ks < 8; ks++) {
            #pragma unroll
            for (int kb = 0; kb < 2; kb++) {
                bf16x8 kf = *(const bf16x8*)((const bf16*)K_l + (kb * 16 + l15) * 264 + ks * 32 + quad * 8);
                sf[kb] = MFMA16(kf, qf[ks], sf[kb]);
            }
        }
        // causal mask (diagonal tiles only); running max
        float mx = -1e30f;
        #pragma unroll
        for (int kb = 0; kb < 2; kb++)
            #pragma unroll
            for (int r = 0; r < 4; r++) {
                float v = sf[kb][r];
                if (kt >= 2 * qt) {
                    int key = kt * 32 + kb * 16 + quad * 4 + r;
                    if (key > qi) v = -1e30f;
                }
                sf[kb][r] = v;
                mx = fmaxf(mx, v);
            }
        mx = fmaxf(mx, __shfl_xor(mx, 16));
        mx = fmaxf(mx, __shfl_xor(mx, 32));
        float mold = m_run;
        float mnew = fmaxf(mold, mx);
        m_run = mnew;
        float a = exp2f(mold - mnew);
        float rs = 0.f;
        #pragma unroll
        for (int kb = 0; kb < 2; kb++)
            #pragma unroll
            for (int r = 0; r < 4; r++) {
                float e = exp2f(sf[kb][r] - mnew);
                sf[kb][r] = e;
                rs += e;
            }
        rs += __shfl_xor(rs, 16);
        rs += __shfl_xor(rs, 32);
        l_run = l_run * a + rs;
        if (__any(mnew > mold)) {
            #pragma unroll
            for (int f = 0; f < 16; f++)
                #pragma unroll
                for (int r = 0; r < 4; r++) o[f][r] *= a;
        }
        // P^T B-fragment via cross-quad shuffles
        bf16x8 pb;
        {
            int srclo = l15 + 32 * (quad & 1);
            #pragma unroll
            for (int j = 0; j < 8; j++) {
                int srcl = srclo + (j >> 2) * 16;
                float e0 = __shfl(sf[0][j & 3], srcl, 64);
                float e1 = __shfl(sf[1][j & 3], srcl, 64);
                pb[j] = (bf16)((quad >> 1) ? e1 : e0);
            }
        }
        // O^T += V^T P^T : A = V^T (m=d, k=key) from LDS
        #pragma unroll
        for (int f = 0; f < 16; f++) {
            bf16x8 vf = *(const bf16x8*)((const bf16*)V_l + (f * 16 + l15) * 34 + quad * 8);
            o[f] = MFMA16(vf, pb, o[f]);
        }
    }

    // epilogue: collision-free store of normalized partial + denom
    float invl = 1.0f / l_run;
    size_t pos = pbase + (size_t)qi;
    if (quad == 0) Dp[pos] = l_run * exp2f(m_run);
    float* orow = Op + pos * 256 + quad * 4;
    #pragma unroll
    for (int f = 0; f < 16; f++) {
        f32x4 v;
        #pragma unroll
        for (int r = 0; r < 4; r++) v[r] = o[f][r] * invl;
        *(f32x4*)(orow + f * 16) = v;
    }
}

// ---------------------------------------------------------------- finalize
// out = (O1*d1 + O2*d2 + O4*d4) / (d1+d2+d4); O1 lives in d_out already.
__global__ void finalize(float* __restrict__ out, const float* __restrict__ O2,
                         const float* __restrict__ O4,
                         const float* __restrict__ D1, const float* __restrict__ D2,
                         const float* __restrict__ D4) {
    int g = blockIdx.x * 256 + threadIdx.x;     // 32768 tokens * 64 chunks
    int t = g >> 6, dc = (g & 63) * 4;
    int b = t >> 13, n = t & 8191;
    float d1 = D1[t];
    float4 o1 = *(float4*)(out + (size_t)t * 256 + dc);
    float ax = o1.x * d1, ay = o1.y * d1, az = o1.z * d1, aw = o1.w * d1;
    float den = d1;
    if ((n & 1) == 0) {
        int pos2 = b * 4096 + (n >> 12) * 2048 + ((n & 4095) >> 1);
        float d2 = D2[pos2];
        const float4 o2 = *(const float4*)(O2 + (size_t)pos2 * 256 + dc);
        ax += o2.x * d2; ay += o2.y * d2; az += o2.z * d2; aw += o2.w * d2;
        den += d2;
    }
    if ((n & 3) == 0) {
        int pos4 = b * 2048 + (n >> 2);
        float d4 = D4[pos4];
        const float4 o4 = *(const float4*)(O4 + (size_t)pos4 * 256 + dc);
        ax += o4.x * d4; ay += o4.y * d4; az += o4.z * d4; aw += o4.w * d4;
        den += d4;
    }
    float inv = 1.0f / den;
    float4 r; r.x = ax * inv; r.y = ay * inv; r.z = az * inv; r.w = aw * inv;
    *(float4*)(out + (size_t)t * 256 + dc) = r;
}

// ---------------------------------------------------------------- launch
extern "C" void kernel_launch(void* const* d_in, const int* in_sizes, int n_in,
                              void* d_out, int out_size, void* d_ws, size_t ws_size,
                              hipStream_t stream) {
    const float* x  = (const float*)d_in[0];
    const float* Wq = (const float*)d_in[1];
    const float* Wk = (const float*)d_in[2];
    const float* Wv = (const float*)d_in[3];
    float* out = (float*)d_out;

    char* ws = (char*)d_ws;
    bf16* Qb   = (bf16*)(ws);                        // 16 MB
    bf16* Kb   = (bf16*)(ws + 16777216);             // 16 MB
    bf16* Vtt1 = (bf16*)(ws + 33554432);             // 16 MB  [16 seg][64 kt][256][32]
    bf16* Vtt2 = (bf16*)(ws + 50331648);             //  8 MB  [8 seg][64][256][32]
    bf16* Vtt4 = (bf16*)(ws + 58720256);             //  4 MB  [4 seg][64][256][32]
    bf16* Wbt  = (bf16*)(ws + 62914560);             // 384 KB
    float* O2  = (float*)(ws + 63307776);            // 16 MB
    float* O4  = (float*)(ws + 80084992);            //  8 MB
    float* D1  = (float*)(ws + 88473600);            // 128 KB
    float* D2  = (float*)(ws + 88604672);            //  64 KB
    float* D4  = (float*)(ws + 88670208);            //  32 KB

    cvt_w<<<768, 256, 0, stream>>>(Wq, Wk, Wv, Wbt);
    qkv_gemm<<<dim3(512, 4, 3), 256, 0, stream>>>(x, Wbt, Qb, Kb, Vtt1, Vtt2, Vtt4);
    attn<<<896, 256, 0, stream>>>(Qb, Kb, Vtt1, Vtt2, Vtt4, out, O2, O4, D1, D2, D4);
    finalize<<<8192, 256, 0, stream>>>(out, O2, O4, D1, D2, D4);
}

// Round 5
// 349.423 us; speedup vs baseline: 2.0335x; 1.6541x over previous
//
#include <hip/hip_runtime.h>
#include <hip/hip_bf16.h>

typedef __bf16 bf16;
typedef unsigned short u16;
typedef bf16 bf16x8 __attribute__((ext_vector_type(8)));
typedef u16  u16x8  __attribute__((ext_vector_type(8)));
typedef u16  u16x4  __attribute__((ext_vector_type(4)));
typedef float f32x4 __attribute__((ext_vector_type(4)));

#define MFMA16(a,b,c) __builtin_amdgcn_mfma_f32_16x16x32_bf16((a),(b),(c),0,0,0)
#define QSCALE 0.09016844005625f   // (1/16) * log2(e)

// W (f32 [c][d]) -> bf16 transposed [which][d][c]
__global__ void cvt_w(const float* __restrict__ Wq, const float* __restrict__ Wk,
                      const float* __restrict__ Wv, bf16* __restrict__ Wbt) {
    int idx = blockIdx.x * 256 + threadIdx.x;
    int which = idx >> 16;
    int rem = idx & 65535;
    int c = rem >> 8, d = rem & 255;
    const float* W = (which == 0) ? Wq : (which == 1) ? Wk : Wv;
    Wbt[(size_t)which * 65536 + d * 256 + c] = (bf16)W[c * 256 + d];
}

// ---------------------------------------------------------------- QKV GEMM
// [32768 x 256] @ [256 x 256] -> Q (prescaled), K row-major; V^T tiled per cfg:
// Vtt_r[segi][kt][256 d][32 keys]  (each 32-key tile = contiguous 16 KB).
__global__ __launch_bounds__(256, 2)
void qkv_gemm(const float* __restrict__ x, const bf16* __restrict__ Wbt,
              bf16* __restrict__ Qb, bf16* __restrict__ Kb,
              bf16* __restrict__ Vtt1, bf16* __restrict__ Vtt2, bf16* __restrict__ Vtt4) {
    __shared__ __align__(16) u16 lA[64 * 136];
    __shared__ __align__(16) u16 lB[64 * 136];
    int mt = blockIdx.x, nt = blockIdx.y, which = blockIdx.z;
    int tid = threadIdx.x, wv = tid >> 6, lane = tid & 63;
    int l15 = lane & 15, quad = lane >> 4;

    f32x4 acc[4] = {};
    const float* Ax = x + (size_t)(mt * 64) * 256;
    const bf16* Bb = Wbt + (size_t)which * 65536 + (size_t)(nt * 64) * 256;
    int row = tid >> 2, c0 = (tid & 3) * 32;

    for (int kh = 0; kh < 2; kh++) {
        __syncthreads();
        #pragma unroll
        for (int i = 0; i < 4; i++) {
            float4 f0 = *(const float4*)(Ax + row * 256 + kh * 128 + c0 + i * 8);
            float4 f1 = *(const float4*)(Ax + row * 256 + kh * 128 + c0 + i * 8 + 4);
            bf16x8 v;
            v[0] = (bf16)f0.x; v[1] = (bf16)f0.y; v[2] = (bf16)f0.z; v[3] = (bf16)f0.w;
            v[4] = (bf16)f1.x; v[5] = (bf16)f1.y; v[6] = (bf16)f1.z; v[7] = (bf16)f1.w;
            *(bf16x8*)((bf16*)lA + row * 136 + c0 + i * 8) = v;
            *(bf16x8*)((bf16*)lB + row * 136 + c0 + i * 8) =
                *(const bf16x8*)(Bb + row * 256 + kh * 128 + c0 + i * 8);
        }
        __syncthreads();
        #pragma unroll
        for (int ks = 0; ks < 4; ks++) {
            bf16x8 a = *(const bf16x8*)((bf16*)lA + (wv * 16 + l15) * 136 + ks * 32 + quad * 8);
            #pragma unroll
            for (int ns = 0; ns < 4; ns++) {
                bf16x8 b2 = *(const bf16x8*)((bf16*)lB + (ns * 16 + l15) * 136 + ks * 32 + quad * 8);
                acc[ns] = MFMA16(a, b2, acc[ns]);
            }
        }
    }

    // Epilogue through LDS for coalesced stores.
    __syncthreads();
    u16* lT = lA;                     // [64][72] u16
    float sc = (which == 0) ? QSCALE : 1.0f;
    if (which < 2) {
        // layout [tok][col]
        #pragma unroll
        for (int ns = 0; ns < 4; ns++)
            #pragma unroll
            for (int r = 0; r < 4; r++) {
                bf16 v = (bf16)(acc[ns][r] * sc);
                lT[(wv * 16 + quad * 4 + r) * 72 + ns * 16 + l15] = *(u16*)&v;
            }
        __syncthreads();
        bf16* outp = (which == 0) ? Qb : Kb;
        int tokl = tid >> 2, ch = tid & 3;
        u16x8 v0 = *(u16x8*)(lT + tokl * 72 + ch * 16);
        u16x8 v1 = *(u16x8*)(lT + tokl * 72 + ch * 16 + 8);
        u16* dst = (u16*)outp + (size_t)(mt * 64 + tokl) * 256 + nt * 64 + ch * 16;
        *(u16x8*)dst = v0;
        *(u16x8*)(dst + 8) = v1;
    } else {
        // layout [col d][tok]
        #pragma unroll
        for (int ns = 0; ns < 4; ns++)
            #pragma unroll
            for (int r = 0; r < 4; r++) {
                bf16 v = (bf16)acc[ns][r];
                lT[(ns * 16 + l15) * 72 + wv * 16 + quad * 4 + r] = *(u16*)&v;
            }
        __syncthreads();
        int gtok = mt * 64;
        int bL = gtok >> 13, n0 = gtok & 8191;
        int d_l = tid >> 2, q = tid & 3;
        int dg = nt * 64 + d_l;
        {   // cfg1: segs of 2048 consecutive tokens; 2 tiles per block
            int s1 = n0 >> 11, j1 = n0 & 2047;           // j1 multiple of 64
            u16* dst = (u16*)Vtt1 + ((size_t)(bL * 4 + s1) * 64 + (j1 >> 5) + (q >> 1)) * 8192
                       + (size_t)dg * 32 + (q & 1) * 16;
            u16x8 a0 = *(u16x8*)(lT + d_l * 72 + q * 16);
            u16x8 a1 = *(u16x8*)(lT + d_l * 72 + q * 16 + 8);
            *(u16x8*)dst = a0; *(u16x8*)(dst + 8) = a1;
        }
        {   // cfg2: even tokens; 32 compacted keys per block = 1 tile
            int s2 = n0 >> 12, j2 = (n0 & 4095) >> 1;    // multiple of 32
            u16x8 e;
            #pragma unroll
            for (int i = 0; i < 8; i++) e[i] = lT[d_l * 72 + q * 16 + 2 * i];
            u16* dst = (u16*)Vtt2 + ((size_t)(bL * 2 + s2) * 64 + (j2 >> 5)) * 8192
                       + (size_t)dg * 32 + q * 8;
            *(u16x8*)dst = e;
        }
        {   // cfg4: tokens %4==0; 16 compacted keys per block = half tile
            int j4 = n0 >> 2;                            // multiple of 16
            u16x4 e;
            #pragma unroll
            for (int i = 0; i < 4; i++) e[i] = lT[d_l * 72 + q * 16 + 4 * i];
            u16* dst = (u16*)Vtt4 + ((size_t)bL * 64 + (j4 >> 5)) * 8192
                       + (size_t)dg * 32 + (j4 & 31) + q * 4;
            *(u16x4*)dst = e;
        }
    }
}

// ---------------------------------------------------------------- attention
// One block = 64 q-rows of one (seg, qt); LDS-staged K and V^T tiles.
// (256,3): 148 regs/wave fits the 170 budget -> NO scratch spills.
__global__ __launch_bounds__(256, 3)
void attn(const bf16* __restrict__ Qb, const bf16* __restrict__ Kb,
          const bf16* __restrict__ Vtt1, const bf16* __restrict__ Vtt2,
          const bf16* __restrict__ Vtt4,
          float* __restrict__ O1, float* __restrict__ O2, float* __restrict__ O4,
          float* __restrict__ D1, float* __restrict__ D2, float* __restrict__ D4) {
    __shared__ __align__(16) u16 K_l[32 * 264];   // 16896 B
    __shared__ __align__(16) u16 V_l[256 * 34];   // 17408 B

    const int item = (int)blockIdx.x;
    const int qt = 31 - (item / 28);              // heavy rows first
    const int seg = item % 28;

    int lr, b, s, w;
    if (seg < 16)      { lr = 0; s = seg >> 2;        b = seg & 3;        w = 2048; }
    else if (seg < 24) { lr = 1; s = (seg - 16) >> 2; b = (seg - 16) & 3; w = 4096; }
    else               { lr = 2; s = 0;               b = seg - 24;       w = 8192; }
    const int rr = 1 << lr;
    const size_t base = (size_t)b * 8192 + (size_t)s * w;      // token = base + j*rr
    const size_t pbase = (size_t)b * (8192 >> lr) + (size_t)s * 2048;
    const int segi = (lr == 0) ? (b * 4 + s) : (lr == 1) ? (b * 2 + s) : b;
    const bf16* Vtt = (lr == 0) ? Vtt1 : (lr == 1) ? Vtt2 : Vtt4;
    const u16* Vseg = (const u16*)Vtt + (size_t)segi * 64 * 8192;  // [64 tiles][256][32]
    float* Op = (lr == 0) ? O1 : (lr == 1) ? O2 : O4;
    float* Dp = (lr == 0) ? D1 : (lr == 1) ? D2 : D4;

    const int tid = threadIdx.x, wv = tid >> 6, lane = tid & 63;
    const int l15 = lane & 15, quad = lane >> 4;

    // Q B-fragments (n = q = l15, k = quad*8 + j)
    const int qi = qt * 64 + wv * 16 + l15;
    const bf16* qp = Qb + (base + (size_t)qi * rr) * 256 + quad * 8;
    bf16x8 qf[8];
    #pragma unroll
    for (int ks = 0; ks < 8; ks++) qf[ks] = *(const bf16x8*)(qp + ks * 32);

    f32x4 o[16] = {};
    float m_run = -1e30f, l_run = 0.f;

    // staging maps (interleaved units: conflict-free LDS writes, contiguous VMEM)
    const int krow = tid >> 3, kc = tid & 7;       // K: unit (kc + 8i), 16B units
    const u16* Kp = (const u16*)Kb + base * 256;
    u16x8 kpre[4], vpre[4];
    {   // prefetch tile 0
        const u16* kp = Kp + (size_t)krow * rr * 256;
        #pragma unroll
        for (int i = 0; i < 4; i++) kpre[i] = *(const u16x8*)(kp + (kc + 8 * i) * 8);
        #pragma unroll
        for (int i = 0; i < 4; i++) vpre[i] = *(const u16x8*)(Vseg + (size_t)(tid + 256 * i) * 8);
    }

    const int nkt = 2 * (qt + 1);
    for (int kt = 0; kt < nkt; kt++) {
        __syncthreads();                    // prev compute done reading LDS
        #pragma unroll
        for (int i = 0; i < 4; i++)
            *(u16x8*)(K_l + krow * 264 + (kc + 8 * i) * 8) = kpre[i];
        #pragma unroll
        for (int i = 0; i < 4; i++)
            *(u16x8*)(V_l + ((tid >> 2) + 64 * i) * 34 + (tid & 3) * 8) = vpre[i];
        __syncthreads();
        if (kt + 1 < nkt) {                 // prefetch next tile (overlaps compute)
            const u16* kp = Kp + (size_t)((kt + 1) * 32 + krow) * rr * 256;
            #pragma unroll
            for (int i = 0; i < 4; i++) kpre[i] = *(const u16x8*)(kp + (kc + 8 * i) * 8);
            const u16* vp = Vseg + (size_t)(kt + 1) * 8192;
            #pragma unroll
            for (int i = 0; i < 4; i++) vpre[i] = *(const u16x8*)(vp + (size_t)(tid + 256 * i) * 8);
        }

        // S^T = K Q^T : A = K rows (m=key), B = Q (n=q)
        f32x4 sf[2] = {};
        #pragma unroll
        for (int ks = 0; ks < 8; ks++) {
            #pragma unroll
            for (int kb = 0; kb < 2; kb++) {
                bf16x8 kf = *(const bf16x8*)((const bf16*)K_l + (kb * 16 + l15) * 264 + ks * 32 + quad * 8);
                sf[kb] = MFMA16(kf, qf[ks], sf[kb]);
            }
        }
        // causal mask (diagonal tiles only); running max
        float mx = -1e30f;
        #pragma unroll
        for (int kb = 0; kb < 2; kb++)
            #pragma unroll
            for (int r = 0; r < 4; r++) {
                float v = sf[kb][r];
                if (kt >= 2 * qt) {
                    int key = kt * 32 + kb * 16 + quad * 4 + r;
                    if (key > qi) v = -1e30f;
                }
                sf[kb][r] = v;
                mx = fmaxf(mx, v);
            }
        mx = fmaxf(mx, __shfl_xor(mx, 16));
        mx = fmaxf(mx, __shfl_xor(mx, 32));
        float mold = m_run;
        float mnew = fmaxf(mold, mx);
        m_run = mnew;
        float a = exp2f(mold - mnew);
        float rs = 0.f;
        #pragma unroll
        for (int kb = 0; kb < 2; kb++)
            #pragma unroll
            for (int r = 0; r < 4; r++) {
                float e = exp2f(sf[kb][r] - mnew);
                sf[kb][r] = e;
                rs += e;
            }
        rs += __shfl_xor(rs, 16);
        rs += __shfl_xor(rs, 32);
        l_run = l_run * a + rs;
        if (__any(mnew > mold)) {
            #pragma unroll
            for (int f = 0; f < 16; f++)
                #pragma unroll
                for (int r = 0; r < 4; r++) o[f][r] *= a;
        }
        // P^T B-fragment via cross-quad shuffles
        bf16x8 pb;
        {
            int srclo = l15 + 32 * (quad & 1);
            #pragma unroll
            for (int j = 0; j < 8; j++) {
                int srcl = srclo + (j >> 2) * 16;
                float e0 = __shfl(sf[0][j & 3], srcl, 64);
                float e1 = __shfl(sf[1][j & 3], srcl, 64);
                pb[j] = (bf16)((quad >> 1) ? e1 : e0);
            }
        }
        // O^T += V^T P^T : A = V^T (m=d, k=key) from LDS
        #pragma unroll
        for (int f = 0; f < 16; f++) {
            bf16x8 vf = *(const bf16x8*)((const bf16*)V_l + (f * 16 + l15) * 34 + quad * 8);
            o[f] = MFMA16(vf, pb, o[f]);
        }
    }

    // epilogue: collision-free store of normalized partial + denom
    float invl = 1.0f / l_run;
    size_t pos = pbase + (size_t)qi;
    if (quad == 0) Dp[pos] = l_run * exp2f(m_run);
    float* orow = Op + pos * 256 + quad * 4;
    #pragma unroll
    for (int f = 0; f < 16; f++) {
        f32x4 v;
        #pragma unroll
        for (int r = 0; r < 4; r++) v[r] = o[f][r] * invl;
        *(f32x4*)(orow + f * 16) = v;
    }
}

// ---------------------------------------------------------------- finalize
// out = (O1*d1 + O2*d2 + O4*d4) / (d1+d2+d4); O1 lives in d_out already.
__global__ void finalize(float* __restrict__ out, const float* __restrict__ O2,
                         const float* __restrict__ O4,
                         const float* __restrict__ D1, const float* __restrict__ D2,
                         const float* __restrict__ D4) {
    int g = blockIdx.x * 256 + threadIdx.x;     // 32768 tokens * 64 chunks
    int t = g >> 6, dc = (g & 63) * 4;
    int b = t >> 13, n = t & 8191;
    float d1 = D1[t];
    float4 o1 = *(float4*)(out + (size_t)t * 256 + dc);
    float ax = o1.x * d1, ay = o1.y * d1, az = o1.z * d1, aw = o1.w * d1;
    float den = d1;
    if ((n & 1) == 0) {
        int pos2 = b * 4096 + (n >> 12) * 2048 + ((n & 4095) >> 1);
        float d2 = D2[pos2];
        const float4 o2 = *(const float4*)(O2 + (size_t)pos2 * 256 + dc);
        ax += o2.x * d2; ay += o2.y * d2; az += o2.z * d2; aw += o2.w * d2;
        den += d2;
    }
    if ((n & 3) == 0) {
        int pos4 = b * 2048 + (n >> 2);
        float d4 = D4[pos4];
        const float4 o4 = *(const float4*)(O4 + (size_t)pos4 * 256 + dc);
        ax += o4.x * d4; ay += o4.y * d4; az += o4.z * d4; aw += o4.w * d4;
        den += d4;
    }
    float inv = 1.0f / den;
    float4 r; r.x = ax * inv; r.y = ay * inv; r.z = az * inv; r.w = aw * inv;
    *(float4*)(out + (size_t)t * 256 + dc) = r;
}

// ---------------------------------------------------------------- launch
extern "C" void kernel_launch(void* const* d_in, const int* in_sizes, int n_in,
                              void* d_out, int out_size, void* d_ws, size_t ws_size,
                              hipStream_t stream) {
    const float* x  = (const float*)d_in[0];
    const float* Wq = (const float*)d_in[1];
    const float* Wk = (const float*)d_in[2];
    const float* Wv = (const float*)d_in[3];
    float* out = (float*)d_out;

    char* ws = (char*)d_ws;
    bf16* Qb   = (bf16*)(ws);                        // 16 MB
    bf16* Kb   = (bf16*)(ws + 16777216);             // 16 MB
    bf16* Vtt1 = (bf16*)(ws + 33554432);             // 16 MB  [16 seg][64 kt][256][32]
    bf16* Vtt2 = (bf16*)(ws + 50331648);             //  8 MB  [8 seg][64][256][32]
    bf16* Vtt4 = (bf16*)(ws + 58720256);             //  4 MB  [4 seg][64][256][32]
    bf16* Wbt  = (bf16*)(ws + 62914560);             // 384 KB
    float* O2  = (float*)(ws + 63307776);            // 16 MB
    float* O4  = (float*)(ws + 80084992);            //  8 MB
    float* D1  = (float*)(ws + 88473600);            // 128 KB
    float* D2  = (float*)(ws + 88604672);            //  64 KB
    float* D4  = (float*)(ws + 88670208);            //  32 KB

    cvt_w<<<768, 256, 0, stream>>>(Wq, Wk, Wv, Wbt);
    qkv_gemm<<<dim3(512, 4, 3), 256, 0, stream>>>(x, Wbt, Qb, Kb, Vtt1, Vtt2, Vtt4);
    attn<<<896, 256, 0, stream>>>(Qb, Kb, Vtt1, Vtt2, Vtt4, out, O2, O4, D1, D2, D4);
    finalize<<<8192, 256, 0, stream>>>(out, O2, O4, D1, D2, D4);
}